// Round 1
// baseline (721.969 us; speedup 1.0000x reference)
//
#include <hip/hip_runtime.h>

#define FEAT 41024
#define HID  256
#define BATCH 2048
#define MTOT 4096
#define BK 64
#define KSPLIT 16
#define MT 256
#define NBK (FEAT / BK)            /* 641 */
#define ACCN ((size_t)MTOT * HID)  /* 1048576 floats per split slice */

typedef float    f32x4  __attribute__((ext_vector_type(4)));
typedef float    f32x16 __attribute__((ext_vector_type(16)));
typedef _Float16 f16x4  __attribute__((ext_vector_type(4)));
typedef _Float16 f16x8  __attribute__((ext_vector_type(8)));

// ---------------- zero kernel (atomic-fallback path only) ----------------
__global__ __launch_bounds__(512) void zero_ws_k(float* __restrict__ p) {
    int i = blockIdx.x * 512 + threadIdx.x;
    ((f32x4*)p)[i] = (f32x4)(0.0f);
}

// ---------------- input-layer GEMM: [4096,41024] x [41024,256]^T ----------------
// grid (16 mtiles, 16 ksplits), 512 threads = 8 waves (4 wm x 2 wn), wave tile 64x128
// of v_mfma_f32_32x32x16_f16. A read from HBM exactly once; W_in LLC-resident.
__global__ __launch_bounds__(512, 2) void gemm_in_k(
    const float* __restrict__ wfeat, const float* __restrict__ bfeat,
    const float* __restrict__ Win, float* __restrict__ part, int use_atomic)
{
    // 64 KB total LDS, XOR-swizzled 16B chunks for conflict-free ds_read_b128
    __shared__ __align__(16) _Float16 As[MT * BK];
    __shared__ __align__(16) _Float16 Bs[HID * BK];

    const int tid   = threadIdx.x;
    const int mtile = blockIdx.x;
    const int split = blockIdx.y;
    const int it_beg = (split * NBK) / KSPLIT;
    const int it_end = ((split + 1) * NBK) / KSPLIT;

    const int m0 = mtile * MT;  // block is entirely white or entirely black rows
    const float* Aptr = (m0 < BATCH) ? (wfeat + (size_t)m0 * FEAT)
                                     : (bfeat + (size_t)(m0 - BATCH) * FEAT);

    const int arow = tid >> 4;  // 0..31 (staging row base)
    const int aseg = tid & 15;  // 0..15 (float4 segment within 64-wide k row)

    const int wid  = tid >> 6;
    const int lane = tid & 63;
    const int l31  = lane & 31;
    const int lh   = lane >> 5;
    const int wm   = wid >> 1;  // 0..3
    const int wn   = wid & 1;   // 0..1

    f32x16 accr[2][4];
    #pragma unroll
    for (int a = 0; a < 2; ++a)
        #pragma unroll
        for (int b = 0; b < 4; ++b)
            accr[a][b] = (f32x16)(0.0f);

    f32x4 pa[8], pb[8];
    {   // prologue prefetch of first k-slab
        const int k0 = it_beg * BK;
        #pragma unroll
        for (int u = 0; u < 8; ++u) {
            const int row = arow + 32 * u;
            pa[u] = *(const f32x4*)(Aptr + (size_t)row * FEAT + k0 + aseg * 4);
            pb[u] = *(const f32x4*)(Win  + (size_t)row * FEAT + k0 + aseg * 4);
        }
    }

    for (int it = it_beg; it < it_end; ++it) {
        __syncthreads();  // previous compute done reading LDS
        #pragma unroll
        for (int u = 0; u < 8; ++u) {
            const int row   = arow + 32 * u;
            const int chunk = (aseg >> 1) ^ (row & 7);           // 16B-chunk XOR swizzle
            const int off   = row * BK + chunk * 8 + (aseg & 1) * 4;
            f16x4 ha, hb;
            #pragma unroll
            for (int e = 0; e < 4; ++e) {
                ha[e] = (_Float16)pa[u][e];
                hb[e] = (_Float16)pb[u][e];
            }
            *(f16x4*)&As[off] = ha;
            *(f16x4*)&Bs[off] = hb;
        }
        __syncthreads();  // tile ready

        if (it + 1 < it_end) {  // prefetch next slab; streams during compute below
            const int k0 = (it + 1) * BK;
            #pragma unroll
            for (int u = 0; u < 8; ++u) {
                const int row = arow + 32 * u;
                pa[u] = *(const f32x4*)(Aptr + (size_t)row * FEAT + k0 + aseg * 4);
                pb[u] = *(const f32x4*)(Win  + (size_t)row * FEAT + k0 + aseg * 4);
            }
        }

        #pragma unroll
        for (int ks = 0; ks < 4; ++ks) {
            f16x8 afr[2], bfr[4];
            #pragma unroll
            for (int mf = 0; mf < 2; ++mf) {
                const int r     = wm * 64 + mf * 32 + l31;
                const int chunk = (ks * 2 + lh) ^ (r & 7);
                afr[mf] = *(const f16x8*)&As[r * BK + chunk * 8];
            }
            #pragma unroll
            for (int nf = 0; nf < 4; ++nf) {
                const int r     = wn * 128 + nf * 32 + l31;
                const int chunk = (ks * 2 + lh) ^ (r & 7);
                bfr[nf] = *(const f16x8*)&Bs[r * BK + chunk * 8];
            }
            #pragma unroll
            for (int mf = 0; mf < 2; ++mf)
                #pragma unroll
                for (int nf = 0; nf < 4; ++nf)
                    accr[mf][nf] = __builtin_amdgcn_mfma_f32_32x32x16_f16(
                        afr[mf], bfr[nf], accr[mf][nf], 0, 0, 0);
        }
    }

    // epilogue: C/D layout col=lane&31, row=(reg&3)+8*(reg>>2)+4*(lane>>5)
    float* dst = part + (use_atomic ? (size_t)0 : (size_t)split * ACCN);
    #pragma unroll
    for (int mf = 0; mf < 2; ++mf)
        #pragma unroll
        for (int nf = 0; nf < 4; ++nf) {
            const int gcol = wn * 128 + nf * 32 + l31;
            #pragma unroll
            for (int r = 0; r < 16; ++r) {
                const int rrow = (r & 3) + 8 * (r >> 2) + 4 * lh;
                const int grow = m0 + wm * 64 + mf * 32 + rrow;
                const size_t idx = (size_t)grow * HID + gcol;
                if (use_atomic) atomicAdd(&dst[idx], accr[mf][nf][r]);
                else            dst[idx] = accr[mf][nf][r];
            }
        }
}

// ---------------- split-K reduce + bias/relu + tiny MLP ----------------
// 256 blocks x 256 threads; wave handles 2 batch rows. Lane owns MLP output i=lane&31;
// half-waves split the 512-wide concat dimension.
__global__ __launch_bounds__(256) void mlp_k(
    const float* __restrict__ part, int nparts,
    const float* __restrict__ b_in,
    const float* __restrict__ W_h1, const float* __restrict__ b_h1,
    const float* __restrict__ W_h2, const float* __restrict__ b_h2,
    const float* __restrict__ W_out, const float* __restrict__ b_out,
    float* __restrict__ out)
{
    __shared__ _Float16 W1h[512 * 32];  // transposed [j][i], XOR-swizzled, 32 KB
    __shared__ float    W2T[32 * 33];   // transposed [ii][i'], padded
    __shared__ float    Wo[32];
    __shared__ float    cbuf[4 * 512];  // per-wave combined vector

    const int tid = threadIdx.x;
    #pragma unroll
    for (int u = 0; u < 64; ++u) {
        const int f = tid + 256 * u;
        const int i = f >> 9, j = f & 511;
        W1h[j * 32 + (i ^ (j & 31))] = (_Float16)W_h1[i * 512 + j];
    }
    #pragma unroll
    for (int u = 0; u < 4; ++u) {
        const int f = tid + 256 * u;
        const int a = f >> 5, b = f & 31;
        W2T[b * 33 + a] = W_h2[a * 32 + b];
    }
    if (tid < 32) Wo[tid] = W_out[tid];
    __syncthreads();

    const int wid = tid >> 6, lane = tid & 63, l31 = lane & 31, lh = lane >> 5;
    const float bh1 = b_h1[l31], bh2 = b_h2[l31], bo = b_out[0];
    float* cw = &cbuf[wid * 512];

    for (int r = 0; r < 2; ++r) {
        const int row = blockIdx.x * 8 + wid * 2 + r;
        const int jb  = lane * 8;  // 0..504; lanes 0-31 white half, 32-63 black half
        const size_t srow = (size_t)(lh ? (row + BATCH) : row) * HID + (jb & 255);
        f32x4 v0 = (f32x4)(0.0f), v1 = (f32x4)(0.0f);
        for (int s = 0; s < nparts; ++s) {
            const float* p = part + (size_t)s * ACCN + srow;
            v0 += *(const f32x4*)p;
            v1 += *(const f32x4*)(p + 4);
        }
        const f32x4 bi0 = *(const f32x4*)(b_in + (jb & 255));
        const f32x4 bi1 = *(const f32x4*)(b_in + (jb & 255) + 4);
        f32x4 c0, c1;
        #pragma unroll
        for (int e = 0; e < 4; ++e) {
            c0[e] = fmaxf(v0[e] + bi0[e], 0.0f);
            c1[e] = fmaxf(v1[e] + bi1[e], 0.0f);
        }
        *(f32x4*)&cw[jb]     = c0;
        *(f32x4*)&cw[jb + 4] = c1;
        __syncthreads();

        // x1[i] over 512-dim: half-waves handle j<256 / j>=256, then fold
        float p1 = 0.0f;
        #pragma unroll 8
        for (int jj = 0; jj < 256; ++jj) {
            const int j = lh * 256 + jj;
            p1 = fmaf((float)W1h[j * 32 + (l31 ^ (jj & 31))], cw[j], p1);
        }
        p1 += __shfl_xor(p1, 32);
        const float x1 = fmaxf(p1 + bh1, 0.0f);

        // x2[i'] = sum_i W_h2[i'][i] * x1[i], broadcast x1 via shfl
        float p2 = 0.0f;
        #pragma unroll
        for (int ii = 0; ii < 32; ++ii) {
            const float xv = __shfl(x1, ii);
            p2 = fmaf(W2T[ii * 33 + l31], xv, p2);
        }
        const float x2 = fmaxf(p2 + bh2, 0.0f);

        float ov = x2 * Wo[l31];
        ov += __shfl_xor(ov, 16);
        ov += __shfl_xor(ov, 8);
        ov += __shfl_xor(ov, 4);
        ov += __shfl_xor(ov, 2);
        ov += __shfl_xor(ov, 1);
        if (lane == 0) out[row] = ov + bo;
        __syncthreads();
    }
}

extern "C" void kernel_launch(void* const* d_in, const int* in_sizes, int n_in,
                              void* d_out, int out_size, void* d_ws, size_t ws_size,
                              hipStream_t stream) {
    const float* wf   = (const float*)d_in[0];
    const float* blf  = (const float*)d_in[1];
    const float* Win  = (const float*)d_in[2];
    const float* bin  = (const float*)d_in[3];
    const float* Wh1  = (const float*)d_in[4];
    const float* bh1  = (const float*)d_in[5];
    const float* Wh2  = (const float*)d_in[6];
    const float* bh2  = (const float*)d_in[7];
    const float* Wout = (const float*)d_in[8];
    const float* bout = (const float*)d_in[9];
    float* out = (float*)d_out;
    float* ws  = (float*)d_ws;

    const size_t need = (size_t)KSPLIT * ACCN * sizeof(float);  // 64 MB
    const int use_atomic = (ws_size < need) ? 1 : 0;

    if (use_atomic) zero_ws_k<<<512, 512, 0, stream>>>(ws);
    dim3 g(MTOT / MT, KSPLIT);
    gemm_in_k<<<g, 512, 0, stream>>>(wf, blf, Win, ws, use_atomic);
    mlp_k<<<BATCH / 8, 256, 0, stream>>>(ws, use_atomic ? 1 : KSPLIT,
                                         bin, Wh1, bh1, Wh2, bh2, Wout, bout, out);
}